// Round 6
// baseline (2672.815 us; speedup 1.0000x reference)
//
#include <hip/hip_runtime.h>
#include <stdint.h>
#include <stddef.h>

// Problem constants
constexpr int V = 32000, E = 256, H = 512, B = 64, T = 512;
constexpr int NTHR = 512;        // 8 waves
constexpr int NBLK = 64;         // 4 groups x 16 blocks
constexpr int BATG = 16;         // batches per group
constexpr int HPB = 32;          // hidden units per block (128 gate rows)

// LDS: Ps ping-pong [2][8 waves][128 rows * 17]
constexpr int PSW = 128 * 17;                        // 2176 floats per wave
constexpr int OFF_PS   = 0;                          // 2*8*2176*4 = 139264
constexpr int OFF_BIAS = OFF_PS + 2 * 8 * PSW * 4;   // 139264
constexpr int OFF_LEN  = OFF_BIAS + 128 * 4;         // 139776
constexpr int LDS_BYTES = OFF_LEN + 64;              // 139840 -> 1 block/CU

constexpr int BHW = B * 512;     // dwords per tagged-h ping-pong buffer

// Output layout (flat fp32): output | hT | cT | mask
constexpr size_t OUT_HT   = (size_t)B * T * H;
constexpr size_t OUT_CT   = OUT_HT + (size_t)B * H;
constexpr size_t OUT_MASK = OUT_CT + (size_t)B * H;

typedef __attribute__((ext_vector_type(8))) short short8;   // 8 bf16
typedef __attribute__((ext_vector_type(4))) float f32x4;
typedef __attribute__((ext_vector_type(4))) unsigned int u32x4;

__device__ __forceinline__ unsigned short f2bf(float f) {   // RNE fp32->bf16
  uint32_t u = __builtin_bit_cast(uint32_t, f);
  return (unsigned short)((u + 0x7fffu + ((u >> 16) & 1u)) >> 16);
}
__device__ __forceinline__ short8 pack_bf8(float4 v0, float4 v1) {
  short8 r;
  r[0] = (short)f2bf(v0.x); r[1] = (short)f2bf(v0.y);
  r[2] = (short)f2bf(v0.z); r[3] = (short)f2bf(v0.w);
  r[4] = (short)f2bf(v1.x); r[5] = (short)f2bf(v1.y);
  r[6] = (short)f2bf(v1.z); r[7] = (short)f2bf(v1.w);
  return r;
}
__device__ __forceinline__ float sigmoidf_fast(float x) {
  return 1.f / (1.f + __expf(-x));
}
__device__ __forceinline__ float tanhf_fast(float x) {   // 1 - 2/(e^2x+1)
  return 1.f - 2.f / (__expf(2.f * x) + 1.f);            // inf-safe both tails
}
// MALL-coherent relaxed agent store (bypasses per-XCD L2)
__device__ __forceinline__ void st_word(uint32_t* p, uint32_t v) {
  __hip_atomic_store(p, v, __ATOMIC_RELAXED, __HIP_MEMORY_SCOPE_AGENT);
}
// one poll iteration: 8x dwordx4 device-scope loads, single wait
__device__ __forceinline__ void ld_tagged_8x4(const uint32_t* p,
    u32x4& r0, u32x4& r1, u32x4& r2, u32x4& r3,
    u32x4& r4, u32x4& r5, u32x4& r6, u32x4& r7) {
  asm volatile(
      "global_load_dwordx4 %0, %8, off sc1\n\t"
      "global_load_dwordx4 %1, %8, off offset:16 sc1\n\t"
      "global_load_dwordx4 %2, %8, off offset:128 sc1\n\t"
      "global_load_dwordx4 %3, %8, off offset:144 sc1\n\t"
      "global_load_dwordx4 %4, %8, off offset:256 sc1\n\t"
      "global_load_dwordx4 %5, %8, off offset:272 sc1\n\t"
      "global_load_dwordx4 %6, %8, off offset:384 sc1\n\t"
      "global_load_dwordx4 %7, %8, off offset:400 sc1\n\t"
      "s_waitcnt vmcnt(0)"
      : "=&v"(r0), "=&v"(r1), "=&v"(r2), "=&v"(r3),
        "=&v"(r4), "=&v"(r5), "=&v"(r6), "=&v"(r7)
      : "v"(p)
      : "memory");
}

__global__ void __launch_bounds__(NTHR, 1)
lstm_mfma(const int* __restrict__ inputs, const int* __restrict__ lengths,
          const int* __restrict__ resets, const float* __restrict__ emb,
          const float* __restrict__ W_ih, const float* __restrict__ W_hh,
          const float* __restrict__ b_ih, const float* __restrict__ b_hh,
          float* __restrict__ out, uint32_t* __restrict__ hw) {
  extern __shared__ char lds[];
  float* Ps = (float*)(lds + OFF_PS);     // [t&1][wave][n(128)*17 + m(16)]
  float* Bias = (float*)(lds + OFF_BIAS);
  int* Lens = (int*)(lds + OFF_LEN);

  const int tid = threadIdx.x;
  const int blk = blockIdx.x;
  const int grp = blk & 3;        // batch group 0..3
  const int rq = blk >> 2;        // block rank in group 0..15
  const int khid = rq * HPB;      // hidden base (32 dims)
  const int b0 = grp * BATG;

  const int w = tid >> 6;         // wave 0..7
  const int L = tid & 63;
  const int lc = L & 15;          // A: batch m | B: gate row n within tile
  const int q = L >> 4;           // quad

  // ---- persistent W fragments (bf16): wf[s][tile]
  // waves 0..3: h side, K = 128w + 32s + 8q (4 frags)
  // waves 4..7: emb side, Ke = 64(w-4) + 32s + 8q (2 frags)
  short8 wf[4][8];
  if (w < 4) {
    #pragma unroll
    for (int s = 0; s < 4; ++s) {
      #pragma unroll
      for (int tl = 0; tl < 8; ++tl) {
        const int n = 16 * tl + lc;
        const int grow = (n >> 5) * H + khid + (n & 31);
        const float* src = W_hh + (size_t)grow * H + 128 * w + 32 * s + 8 * q;
        wf[s][tl] = pack_bf8(*(const float4*)src, *(const float4*)(src + 4));
      }
    }
  } else {
    #pragma unroll
    for (int s = 0; s < 2; ++s) {
      #pragma unroll
      for (int tl = 0; tl < 8; ++tl) {
        const int n = 16 * tl + lc;
        const int grow = (n >> 5) * H + khid + (n & 31);
        const float* src = W_ih + (size_t)grow * E + 64 * (w - 4) + 32 * s + 8 * q;
        wf[s][tl] = pack_bf8(*(const float4*)src, *(const float4*)(src + 4));
      }
    }
  }
  if (tid < 128) {
    const int grow = (tid >> 5) * H + khid + (tid & 31);
    Bias[tid] = b_ih[grow] + b_hh[grow];
  }
  if (tid < 16) Lens[tid] = lengths[b0 + tid];
  {  // mask output, fused: 64 blocks x 512 threads = B*T
    int i = blk * 512 + tid;
    int mb = i >> 9, mt = i & (T - 1);
    out[OUT_MASK + i] = (mt < lengths[mb]) ? 1.f : 0.f;
  }
  // (no init barrier needed: Bias/Lens are first read after the t=0
  //  reduce __syncthreads; tagged-word scheme needs no flag init —
  //  harness re-poisons d_ws to 0xAA, and 0xAAAA != any tag in 1..511)

  const int jj = tid & 31;        // epilogue: hidden dim 0..31
  const int bb = tid >> 5;        // epilogue: batch 0..15

  float carry_h = 0.f, carry_c = 0.f;

  for (int t = 0; t < T; ++t) {
    float* Pcur = Ps + (t & 1) * (8 * PSW);

    // ---- pre-barrier independent work
    float rr = (float)resets[(b0 + bb) * T + t];
    f32x4 acc[8];
    #pragma unroll
    for (int tl = 0; tl < 8; ++tl) acc[tl] = (f32x4){0.f, 0.f, 0.f, 0.f};

    if (w >= 4) {                 // emb side: no cross-block dependence
      const int tok = inputs[(b0 + lc) * T + t];
      const float* eb = emb + (size_t)tok * E + 64 * (w - 4) + 8 * q;
      short8 a0 = pack_bf8(*(const float4*)eb, *(const float4*)(eb + 4));
      short8 a1 = pack_bf8(*(const float4*)(eb + 32), *(const float4*)(eb + 36));
      #pragma unroll
      for (int tl = 0; tl < 8; ++tl)
        acc[tl] = __builtin_amdgcn_mfma_f32_16x16x32_bf16(a0, wf[0][tl], acc[tl], 0, 0, 0);
      #pragma unroll
      for (int tl = 0; tl < 8; ++tl)
        acc[tl] = __builtin_amdgcn_mfma_f32_16x16x32_bf16(a1, wf[1][tl], acc[tl], 0, 0, 0);
    } else if (t > 0) {
      // ---- h side: poll self-validating tagged words (whole K-quarter per
      // iteration, one vmcnt). Wave w depends only on producers 4w..4w+3.
      const uint32_t* p = hw + (size_t)(t & 1) * BHW +
                          (size_t)(b0 + lc) * 512 + 128 * w + 8 * q;
      const uint32_t expt = (uint32_t)t << 16;
      u32x4 r0, r1, r2, r3, r4, r5, r6, r7;
      for (;;) {
        ld_tagged_8x4(p, r0, r1, r2, r3, r4, r5, r6, r7);
        uint32_t d = 0;
        #pragma unroll
        for (int j = 0; j < 4; ++j) {
          d |= (r0[j] ^ expt) & 0xffff0000u;
          d |= (r1[j] ^ expt) & 0xffff0000u;
          d |= (r2[j] ^ expt) & 0xffff0000u;
          d |= (r3[j] ^ expt) & 0xffff0000u;
          d |= (r4[j] ^ expt) & 0xffff0000u;
          d |= (r5[j] ^ expt) & 0xffff0000u;
          d |= (r6[j] ^ expt) & 0xffff0000u;
          d |= (r7[j] ^ expt) & 0xffff0000u;
        }
        if (__all(d == 0)) break;
        __builtin_amdgcn_s_sleep(1);
      }
      u32x4 rl[8] = {r0, r1, r2, r3, r4, r5, r6, r7};
      #pragma unroll
      for (int s = 0; s < 4; ++s) {
        short8 a;
        #pragma unroll
        for (int j = 0; j < 4; ++j) {
          a[j]     = (short)(rl[2 * s][j] & 0xffffu);
          a[4 + j] = (short)(rl[2 * s + 1][j] & 0xffffu);
        }
        #pragma unroll
        for (int tl = 0; tl < 8; ++tl)
          acc[tl] = __builtin_amdgcn_mfma_f32_16x16x32_bf16(a, wf[s][tl], acc[tl], 0, 0, 0);
      }
    }

    // partials: D[m=4q+reg][n=16tl+lc] -> Pcur[w*PSW + n*17 + m]
    #pragma unroll
    for (int tl = 0; tl < 8; ++tl)
      *(f32x4*)(Pcur + w * PSW + (16 * tl + lc) * 17 + 4 * q) = acc[tl];
    __syncthreads();              // the ONLY per-step block sync

    // ---- fused reduce + activations + state update (all 512 threads)
    float g4[4];
    #pragma unroll
    for (int gi = 0; gi < 4; ++gi) {
      const int n = gi * 32 + jj;
      float s = Bias[n];
      #pragma unroll
      for (int ww = 0; ww < 8; ++ww) s += Pcur[ww * PSW + n * 17 + bb];
      g4[gi] = s;
    }
    float ig = sigmoidf_fast(g4[0]);
    float fg = sigmoidf_fast(g4[1]);
    float gg = tanhf_fast(g4[2]);
    float og = sigmoidf_fast(g4[3]);
    float c_new = fg * carry_c + ig * gg;
    float h_new = og * tanhf_fast(c_new);
    bool live = (t < Lens[bb]);
    float h_next = live ? h_new : carry_h;   // carry regs are exact fp32
    float c_next = live ? c_new : carry_c;
    carry_h = h_next * (1.f - rr);
    carry_c = c_next * (1.f - rr);

    // post tagged h word FIRST (critical path): (t+1)<<16 | bf16(h)
    if (t < T - 1) {
      uint32_t word = ((uint32_t)(t + 1) << 16) | (uint32_t)f2bf(carry_h);
      st_word(hw + (size_t)((t + 1) & 1) * BHW +
                  (size_t)(b0 + bb) * 512 + 32 * rq + jj, word);
    }
    // HBM output store off the critical path (drains at next reduce barrier)
    out[((size_t)(b0 + bb) * T + t) * H + khid + jj] = h_next;
  }
  out[OUT_HT + (size_t)(b0 + bb) * H + khid + jj] = carry_h;
  out[OUT_CT + (size_t)(b0 + bb) * H + khid + jj] = carry_c;
}

extern "C" void kernel_launch(void* const* d_in, const int* in_sizes, int n_in,
                              void* d_out, int out_size, void* d_ws, size_t ws_size,
                              hipStream_t stream) {
  const int* inputs    = (const int*)d_in[0];
  const int* lengths   = (const int*)d_in[1];
  const int* resets    = (const int*)d_in[2];
  const float* emb     = (const float*)d_in[3];
  const float* W_ih    = (const float*)d_in[4];
  const float* W_hh    = (const float*)d_in[5];
  const float* b_ih    = (const float*)d_in[6];
  const float* b_hh    = (const float*)d_in[7];
  float* out = (float*)d_out;

  // ws: [0, 256KB): tagged h ping-pong buffers (2 x 128KB). No flags, no
  // memset — stale tags are impossible (harness poisons ws to 0xAA; tag
  // range is 1..511, 0xAAAA doesn't alias).
  uint32_t* hw = (uint32_t*)d_ws;

  hipFuncSetAttribute((const void*)lstm_mfma,
                      hipFuncAttributeMaxDynamicSharedMemorySize, LDS_BYTES);

  lstm_mfma<<<NBLK, NTHR, LDS_BYTES, stream>>>(
      inputs, lengths, resets, emb, W_ih, W_hh, b_ih, b_hh, out, hw);
}